// Round 13
// baseline (290.618 us; speedup 1.0000x reference)
//
#include <hip/hip_runtime.h>
#include <hip/hip_bf16.h>
#include <cstddef>

#define D_MODEL 1024
#define M_ROWS  4096
#define BN_EPS  1e-3f
#define C_EXP2  0.18033688011112042f   // 0.125 * log2(e)
#define INV_N   (1.0f / 4096.0f)

typedef __attribute__((ext_vector_type(8))) short short8;
typedef __attribute__((ext_vector_type(4))) short short4v;
typedef __attribute__((ext_vector_type(8))) unsigned short ushortx8;
typedef __attribute__((ext_vector_type(4))) float f32x4;

__device__ __forceinline__ unsigned short f2bf(float f) {
    __hip_bfloat16 h = __float2bfloat16(f);
    return *reinterpret_cast<unsigned short*>(&h);
}
__device__ __forceinline__ float bf2f(unsigned short u) {
    return __uint_as_float(((unsigned)u) << 16);
}
__device__ __forceinline__ unsigned int cvt_pk_bf16(float lo, float hi) {
    unsigned int r;
    asm volatile("v_cvt_pk_bf16_f32 %0, %1, %2" : "=v"(r) : "v"(lo), "v"(hi));
    return r;
}

// ---------------------------------------------------------------------------
// bf16 MFMA GEMM, 64x128 tile, BK=32, 4 waves (2x2, wave-tile 32x64), 24KB LDS.
// High block count (N=3072: 1536 blocks ~4-6/CU; N=1024: 512 blocks = 2/CU)
// hides the per-K-step barrier drain that low co-residency cannot.
// MODE 0: C = bf16(relu(A@Bt^T + bias))             (QKV, FFN1)
// MODE 1: S = relu(..)+resid; bf16 + channel stats  (FFN2)
// MODE 2: S = A@Bt^T; bf16 + channel stats          (embed)
// bias selected from {b0,b1,b2} by col/1024 (QKV concat, no extra kernel).
// ---------------------------------------------------------------------------
template<int MODE>
__global__ __launch_bounds__(256)
void gemm64_bf16_kernel(const unsigned short* __restrict__ A,
                        const unsigned short* __restrict__ Bt,
                        const float* __restrict__ b0, const float* __restrict__ b1,
                        const float* __restrict__ b2,
                        unsigned short* __restrict__ Cout,
                        const unsigned short* __restrict__ resid,
                        float* __restrict__ accp, int N, int Kd) {
    __shared__ unsigned short As[2][64 * 32];
    __shared__ unsigned short Bs[2][128 * 32];
    const int tid = threadIdx.x;
    const int lane = tid & 63;
    const int w = tid >> 6;
    const int wr = w >> 1, wc = w & 1;
    const int rowBase = blockIdx.y * 64;
    const int colBase = blockIdx.x * 128;

    // A: 256 chunks (64 rows x 4 k-chunks), one per thread
    const int ra = tid >> 2;
    const int ca = (tid & 3) ^ ((ra >> 1) & 3);
    const size_t aOff = (size_t)(rowBase + ra) * Kd + ca * 8;
    // B: 512 chunks, two per thread
    const int chunk0 = w * 64 + lane;
    const int r0 = chunk0 >> 2;
    const int c0 = (chunk0 & 3) ^ ((r0 >> 1) & 3);
    const int chunk1 = 256 + chunk0;
    const int r1 = chunk1 >> 2;
    const int c1 = (chunk1 & 3) ^ ((r1 >> 1) & 3);
    const size_t bOff0 = (size_t)(colBase + r0) * Kd + c0 * 8;
    const size_t bOff1 = (size_t)(colBase + r1) * Kd + c1 * 8;
    const int ldsA = (w * 64) * 8;
    const int ldsB0 = (w * 64) * 8;
    const int ldsB1 = (256 + w * 64) * 8;

    f32x4 acc[2][4];
    #pragma unroll
    for (int m = 0; m < 2; ++m)
        #pragma unroll
        for (int n = 0; n < 4; ++n)
            acc[m][n] = (f32x4){0.f, 0.f, 0.f, 0.f};

    #define STAGE(buf, kt) do {                                                   \
        const int k0_ = (kt) << 5;                                                \
        __builtin_amdgcn_global_load_lds(                                         \
            (const __attribute__((address_space(1))) void*)(A + aOff + k0_),      \
            (__attribute__((address_space(3))) void*)(&As[buf][ldsA]), 16, 0, 0); \
        __builtin_amdgcn_global_load_lds(                                         \
            (const __attribute__((address_space(1))) void*)(Bt + bOff0 + k0_),    \
            (__attribute__((address_space(3))) void*)(&Bs[buf][ldsB0]), 16, 0, 0);\
        __builtin_amdgcn_global_load_lds(                                         \
            (const __attribute__((address_space(1))) void*)(Bt + bOff1 + k0_),    \
            (__attribute__((address_space(3))) void*)(&Bs[buf][ldsB1]), 16, 0, 0);\
    } while (0)

    const int NT = Kd >> 5;
    STAGE(0, 0);

    const int kb = lane >> 4;
    const int s = kb ^ ((lane >> 1) & 3);   // wr*32 / wc*64 contribute 0 mod 4 after >>1
    const int rA = wr * 32 + (lane & 15);
    const int rB = wc * 64 + (lane & 15);

    for (int t = 0; t < NT; ++t) {
        __syncthreads();
        if (t + 1 < NT) STAGE((t + 1) & 1, t + 1);
        const unsigned short* as = As[t & 1];
        const unsigned short* bs = Bs[t & 1];
        short8 a[2], b[4];
        #pragma unroll
        for (int m = 0; m < 2; ++m)
            a[m] = *(const short8*)&as[(rA + m * 16) * 32 + s * 8];
        #pragma unroll
        for (int n = 0; n < 4; ++n)
            b[n] = *(const short8*)&bs[(rB + n * 16) * 32 + s * 8];
        #pragma unroll
        for (int m = 0; m < 2; ++m)
            #pragma unroll
            for (int n = 0; n < 4; ++n)
                acc[m][n] = __builtin_amdgcn_mfma_f32_16x16x32_bf16(
                    a[m], b[n], acc[m][n], 0, 0, 0);
    }
    #undef STAGE

    const int cRow0 = rowBase + wr * 32 + (lane >> 4) * 4;
    const int cCol0 = colBase + wc * 64 + (lane & 15);
    float cs[4] = {}, cq[4] = {};
    #pragma unroll
    for (int n = 0; n < 4; ++n) {
        const int col = cCol0 + n * 16;
        float bv = 0.0f;
        if (MODE != 2) {
            const float* bp = (col < 1024) ? b0 : (col < 2048) ? b1 : b2;
            bv = bp[col & 1023];
        }
        #pragma unroll
        for (int m = 0; m < 2; ++m)
            #pragma unroll
            for (int r = 0; r < 4; ++r) {
                const int row = cRow0 + m * 16 + r;
                float v = acc[m][n][r];
                if (MODE != 2) v = fmaxf(v + bv, 0.0f);
                if (MODE == 1) v += bf2f(resid[(size_t)row * N + col]);
                if (MODE != 0) { cs[n] += v; cq[n] += v * v; }
                Cout[(size_t)row * N + col] = f2bf(v);
            }
    }
    if (MODE != 0) {
        #pragma unroll
        for (int n = 0; n < 4; ++n) {
            cs[n] += __shfl_xor(cs[n], 16); cs[n] += __shfl_xor(cs[n], 32);
            cq[n] += __shfl_xor(cq[n], 16); cq[n] += __shfl_xor(cq[n], 32);
        }
        if (lane < 16) {
            #pragma unroll
            for (int n = 0; n < 4; ++n) {
                const int col = colBase + wc * 64 + lane + n * 16;
                atomicAdd(&accp[col], cs[n]);
                atomicAdd(&accp[D_MODEL + col], cq[n]);
            }
        }
    }
}

// ---------------------------------------------------------------------------
// prep (single launch): z<8 -> weight transpose+cvt (2 layers x {Wq,Wk,Wv,Wc1});
// z==8 -> x cvt (b<128), W_embed^T (b in 128..143), zero accum (b==144)
// ---------------------------------------------------------------------------
__global__ __launch_bounds__(256)
void prep_kernel(const float* __restrict__ Wq, const float* __restrict__ Wk,
                 const float* __restrict__ Wv, const float* __restrict__ Wc1,
                 const float* __restrict__ x, const float* __restrict__ Wemb,
                 unsigned short* __restrict__ Wtqkv, unsigned short* __restrict__ Wtc1,
                 unsigned short* __restrict__ xbf, unsigned short* __restrict__ Wembt,
                 float* __restrict__ accum) {
    const int z = blockIdx.z;
    const int tid = threadIdx.x;
    if (z < 8) {
        const int layer = z >> 2, typ = z & 3;
        const size_t wo = (size_t)layer * 1048576;
        const float* src;
        unsigned short* dst;
        if (typ == 0)      { src = Wq + wo;  dst = Wtqkv + layer * 3145728; }
        else if (typ == 1) { src = Wk + wo;  dst = Wtqkv + layer * 3145728 + 1048576; }
        else if (typ == 2) { src = Wv + wo;  dst = Wtqkv + layer * 3145728 + 2097152; }
        else               { src = Wc1 + wo; dst = Wtc1 + layer * 1048576; }
        __shared__ float T[64][65];
        const int kBase = blockIdx.y * 64;
        const int nBase = blockIdx.x * 64;
        const int rr = tid >> 4;
        const int c4 = (tid & 15) * 4;
        #pragma unroll
        for (int i = 0; i < 4; ++i) {
            const int k = i * 16 + rr;
            const float4 v = *reinterpret_cast<const float4*>(
                &src[(size_t)(kBase + k) * 1024 + nBase + c4]);
            T[k][c4] = v.x; T[k][c4 + 1] = v.y; T[k][c4 + 2] = v.z; T[k][c4 + 3] = v.w;
        }
        __syncthreads();
        #pragma unroll
        for (int i = 0; i < 4; ++i) {
            const int n = i * 16 + rr;
            ushort4 o;
            o.x = f2bf(T[c4 + 0][n]); o.y = f2bf(T[c4 + 1][n]);
            o.z = f2bf(T[c4 + 2][n]); o.w = f2bf(T[c4 + 3][n]);
            *reinterpret_cast<ushort4*>(&dst[(size_t)(nBase + n) * 1024 + kBase + c4]) = o;
        }
        return;
    }
    const int b = blockIdx.y * 16 + blockIdx.x;
    if (b < 128) {
        const size_t base = (size_t)b * 2048 + tid * 8;
        const float4 v0 = *reinterpret_cast<const float4*>(&x[base]);
        const float4 v1 = *reinterpret_cast<const float4*>(&x[base + 4]);
        ushortx8 o;
        o[0] = f2bf(v0.x); o[1] = f2bf(v0.y); o[2] = f2bf(v0.z); o[3] = f2bf(v0.w);
        o[4] = f2bf(v1.x); o[5] = f2bf(v1.y); o[6] = f2bf(v1.z); o[7] = f2bf(v1.w);
        *reinterpret_cast<ushortx8*>(&xbf[base]) = o;
    } else if (b < 144) {
        __shared__ float T[64][65];
        const int nBase = (b - 128) * 64;
        const int rr = tid >> 4;
        const int c4 = (tid & 15) * 4;
        #pragma unroll
        for (int i = 0; i < 4; ++i) {
            const int k = i * 16 + rr;
            const float4 v = *reinterpret_cast<const float4*>(
                &Wemb[(size_t)k * 1024 + nBase + c4]);
            T[k][c4] = v.x; T[k][c4 + 1] = v.y; T[k][c4 + 2] = v.z; T[k][c4 + 3] = v.w;
        }
        __syncthreads();
        #pragma unroll
        for (int i = 0; i < 4; ++i) {
            const int n = i * 16 + rr;
            ushort4 o;
            o.x = f2bf(T[c4 + 0][n]); o.y = f2bf(T[c4 + 1][n]);
            o.z = f2bf(T[c4 + 2][n]); o.w = f2bf(T[c4 + 3][n]);
            *reinterpret_cast<ushort4*>(&Wembt[(size_t)(nBase + n) * 64 + c4]) = o;
        }
    } else if (b == 144) {
        for (int j = tid; j < 5 * 2048; j += 256) accum[j] = 0.0f;
    }
}

// ---------------------------------------------------------------------------
// MFMA flash attention + fused residual + BN stats. (unchanged, proven)
// ---------------------------------------------------------------------------
__global__ __launch_bounds__(256)
void attn_kernel(const unsigned short* __restrict__ QKV,
                 const unsigned short* __restrict__ Ebf,
                 unsigned short* __restrict__ Sbf,
                 float* __restrict__ accp) {
    __shared__ unsigned short Qs[128 * 64];
    __shared__ unsigned short Ks[2][64 * 64];
    __shared__ unsigned short Vt[2][64 * 72];

    const int tid = threadIdx.x;
    const int lane = tid & 63;
    const int w = tid >> 6;
    const int m = lane & 15;
    const int g = lane >> 4;
    const int l7 = lane & 7;
    const int qt = blockIdx.x, hh = blockIdx.y, bb = blockIdx.z;
    const int colB = hh * 64;
    const size_t rowQ = (size_t)bb * 512 + qt * 128;
    const size_t rowKV = (size_t)bb * 512;

    const int vk0 = (tid & 31) * 2;
    const int vcv = tid >> 5;

    #define STAGE_K(buf, kt) do {                                                  \
        const size_t kb_ = rowKV + (size_t)(kt) * 64;                              \
        _Pragma("unroll")                                                          \
        for (int i_ = 0; i_ < 2; ++i_) {                                           \
            const int c_ = w * 128 + i_ * 64 + lane;                               \
            const int r_ = c_ >> 3;                                                \
            const int gc_ = (c_ & 7) ^ (r_ & 7);                                   \
            __builtin_amdgcn_global_load_lds(                                      \
                (const __attribute__((address_space(1))) void*)                    \
                    (QKV + (kb_ + r_) * 3072 + 1024 + colB + gc_ * 8),             \
                (__attribute__((address_space(3))) void*)                          \
                    (&Ks[buf][(w * 128 + i_ * 64) * 8]), 16, 0, 0);                \
        }                                                                          \
    } while (0)

    #define LOAD_V(kt) do {                                                        \
        const size_t kb_ = rowKV + (size_t)(kt) * 64;                              \
        vst0 = *(const ushortx8*)(QKV + (kb_ + vk0) * 3072 + 2048 + colB + vcv * 8);\
        vst1 = *(const ushortx8*)(QKV + (kb_ + vk0 + 1) * 3072 + 2048 + colB + vcv * 8);\
    } while (0)

    #define WRITE_V(buf) do {                                                      \
        _Pragma("unroll")                                                          \
        for (int j_ = 0; j_ < 8; ++j_) {                                           \
            const int d_ = vcv * 8 + j_;                                           \
            unsigned int pk_ = (unsigned int)(unsigned short)vst0[j_] |            \
                               ((unsigned int)(unsigned short)vst1[j_] << 16);     \
            *(unsigned int*)&Vt[buf][d_ * 72 + vk0] = pk_;                         \
        }                                                                          \
    } while (0)

    ushortx8 vst0, vst1;

    #pragma unroll
    for (int i = 0; i < 4; ++i) {
        const int c = w * 256 + i * 64 + lane;
        const int r = c >> 3;
        const int gc = (c & 7) ^ (r & 7);
        __builtin_amdgcn_global_load_lds(
            (const __attribute__((address_space(1))) void*)
                (QKV + (rowQ + r) * 3072 + colB + gc * 8),
            (__attribute__((address_space(3))) void*)
                (&Qs[(w * 256 + i * 64) * 8]), 16, 0, 0);
    }
    STAGE_K(0, 0);
    LOAD_V(0);
    WRITE_V(0);
    __syncthreads();

    short8 qb[2][2];
    #pragma unroll
    for (int nf = 0; nf < 2; ++nf)
        #pragma unroll
        for (int ks = 0; ks < 2; ++ks)
            qb[nf][ks] = *(const short8*)&Qs[(w * 32 + 16 * nf + m) * 64 +
                                             ((g + 4 * ks) ^ l7) * 8];

    f32x4 o[2][4];
    #pragma unroll
    for (int nf = 0; nf < 2; ++nf)
        #pragma unroll
        for (int dn = 0; dn < 4; ++dn)
            o[nf][dn] = (f32x4){0.f, 0.f, 0.f, 0.f};
    float mr[2] = {-1e30f, -1e30f};
    float lsm[2] = {0.f, 0.f};

    for (int kt = 0; kt < 8; ++kt) {
        const int cur = kt & 1, nxt = cur ^ 1;
        if (kt < 7) { STAGE_K(nxt, kt + 1); LOAD_V(kt + 1); }

        f32x4 st[4][2];
        #pragma unroll
        for (int mf = 0; mf < 4; ++mf)
            #pragma unroll
            for (int nf = 0; nf < 2; ++nf)
                st[mf][nf] = (f32x4){0.f, 0.f, 0.f, 0.f};
        #pragma unroll
        for (int ks = 0; ks < 2; ++ks) {
            short8 a[4];
            #pragma unroll
            for (int mf = 0; mf < 4; ++mf)
                a[mf] = *(const short8*)&Ks[cur][(m + 16 * mf) * 64 +
                                                 ((g + 4 * ks) ^ l7) * 8];
            __builtin_amdgcn_s_setprio(1);
            #pragma unroll
            for (int mf = 0; mf < 4; ++mf)
                #pragma unroll
                for (int nf = 0; nf < 2; ++nf)
                    st[mf][nf] = __builtin_amdgcn_mfma_f32_16x16x32_bf16(
                        a[mf], qb[nf][ks], st[mf][nf], 0, 0, 0);
            __builtin_amdgcn_s_setprio(0);
        }

        float pmax[2];
        #pragma unroll
        for (int nf = 0; nf < 2; ++nf) {
            float a0 = fmaxf(fmaxf(st[0][nf][0], st[0][nf][1]),
                             fmaxf(st[0][nf][2], st[0][nf][3]));
            float a1 = fmaxf(fmaxf(st[1][nf][0], st[1][nf][1]),
                             fmaxf(st[1][nf][2], st[1][nf][3]));
            float a2 = fmaxf(fmaxf(st[2][nf][0], st[2][nf][1]),
                             fmaxf(st[2][nf][2], st[2][nf][3]));
            float a3 = fmaxf(fmaxf(st[3][nf][0], st[3][nf][1]),
                             fmaxf(st[3][nf][2], st[3][nf][3]));
            float mx = fmaxf(fmaxf(a0, a1), fmaxf(a2, a3));
            mx = fmaxf(mx, __shfl_xor(mx, 16));
            mx = fmaxf(mx, __shfl_xor(mx, 32));
            pmax[nf] = mx;
        }
        const int need = (pmax[0] - mr[0] > 64.f) || (pmax[1] - mr[1] > 64.f);
        if (__any(need)) {
            float al[2];
            #pragma unroll
            for (int nf = 0; nf < 2; ++nf) {
                const float mn = fmaxf(mr[nf], pmax[nf]);
                al[nf] = exp2f((mr[nf] - mn) * C_EXP2);
                lsm[nf] *= al[nf];
                mr[nf] = mn;
            }
            #pragma unroll
            for (int nf = 0; nf < 2; ++nf)
                #pragma unroll
                for (int r = 0; r < 4; ++r) {
                    const float av = __shfl(al[nf], 4 * g + r);
                    #pragma unroll
                    for (int dn = 0; dn < 4; ++dn)
                        o[nf][dn][r] *= av;
                }
        }

        float pf[2][4][4];
        #pragma unroll
        for (int nf = 0; nf < 2; ++nf) {
            const float mc = mr[nf] * C_EXP2;
            float s0 = 0.f, s1 = 0.f, s2 = 0.f, s3 = 0.f;
            #pragma unroll
            for (int mf = 0; mf < 4; ++mf) {
                float p0 = exp2f(fmaf(st[mf][nf][0], C_EXP2, -mc));
                float p1 = exp2f(fmaf(st[mf][nf][1], C_EXP2, -mc));
                float p2 = exp2f(fmaf(st[mf][nf][2], C_EXP2, -mc));
                float p3 = exp2f(fmaf(st[mf][nf][3], C_EXP2, -mc));
                pf[nf][mf][0] = p0; pf[nf][mf][1] = p1;
                pf[nf][mf][2] = p2; pf[nf][mf][3] = p3;
                s0 += p0; s1 += p1; s2 += p2; s3 += p3;
            }
            float ls = (s0 + s1) + (s2 + s3);
            ls += __shfl_xor(ls, 16);
            ls += __shfl_xor(ls, 32);
            lsm[nf] += ls;
        }

        if (kt < 7) WRITE_V(nxt);

        short8 pb[2][2];
        #pragma unroll
        for (int nf = 0; nf < 2; ++nf)
            #pragma unroll
            for (int ks = 0; ks < 2; ++ks) {
                union { unsigned int u[4]; short8 s; } cv;
                cv.u[0] = cvt_pk_bf16(pf[nf][2 * ks][0], pf[nf][2 * ks][1]);
                cv.u[1] = cvt_pk_bf16(pf[nf][2 * ks][2], pf[nf][2 * ks][3]);
                cv.u[2] = cvt_pk_bf16(pf[nf][2 * ks + 1][0], pf[nf][2 * ks + 1][1]);
                cv.u[3] = cvt_pk_bf16(pf[nf][2 * ks + 1][2], pf[nf][2 * ks + 1][3]);
                pb[nf][ks] = cv.s;
            }

        #pragma unroll
        for (int ks = 0; ks < 2; ++ks) {
            short8 vb[4];
            #pragma unroll
            for (int dn = 0; dn < 4; ++dn) {
                const int d = m + 16 * dn;
                const short4v lo = *(const short4v*)&Vt[cur][d * 72 + 4 * g + 32 * ks];
                const short4v hi = *(const short4v*)&Vt[cur][d * 72 + 4 * g + 16 + 32 * ks];
                vb[dn] = __builtin_shufflevector(lo, hi, 0, 1, 2, 3, 4, 5, 6, 7);
            }
            __builtin_amdgcn_s_setprio(1);
            #pragma unroll
            for (int nf = 0; nf < 2; ++nf)
                #pragma unroll
                for (int dn = 0; dn < 4; ++dn)
                    o[nf][dn] = __builtin_amdgcn_mfma_f32_16x16x32_bf16(
                        pb[nf][ks], vb[dn], o[nf][dn], 0, 0, 0);
            __builtin_amdgcn_s_setprio(0);
        }
        __syncthreads();
    }

    float cs[4] = {}, cq[4] = {};
    #pragma unroll
    for (int nf = 0; nf < 2; ++nf) {
        const float inv = 1.0f / lsm[nf];
        #pragma unroll
        for (int r = 0; r < 4; ++r) {
            const float sc = __shfl(inv, 4 * g + r);
            const size_t row = rowQ + w * 32 + 16 * nf + 4 * g + r;
            #pragma unroll
            for (int dn = 0; dn < 4; ++dn) {
                const int ch = colB + 16 * dn + m;
                const float sv = o[nf][dn][r] * sc + bf2f(Ebf[row * D_MODEL + ch]);
                Sbf[row * D_MODEL + ch] = f2bf(sv);
                cs[dn] += sv; cq[dn] += sv * sv;
            }
        }
    }
    #pragma unroll
    for (int dn = 0; dn < 4; ++dn) {
        cs[dn] += __shfl_xor(cs[dn], 16); cs[dn] += __shfl_xor(cs[dn], 32);
        cq[dn] += __shfl_xor(cq[dn], 16); cq[dn] += __shfl_xor(cq[dn], 32);
    }
    if (lane < 16) {
        #pragma unroll
        for (int dn = 0; dn < 4; ++dn) {
            atomicAdd(&accp[colB + 16 * dn + lane], cs[dn]);
            atomicAdd(&accp[D_MODEL + colB + 16 * dn + lane], cq[dn]);
        }
    }
    #undef STAGE_K
    #undef LOAD_V
    #undef WRITE_V
}

// ---------------------------------------------------------------------------
// BN apply with inlined stats->coef (unchanged, proven)
// ---------------------------------------------------------------------------
template<bool FINAL>
__global__ __launch_bounds__(256)
void bn_apply_kernel(const unsigned short* __restrict__ S,
                     const float* __restrict__ accum,
                     const float* __restrict__ gamma,
                     const float* __restrict__ beta,
                     unsigned short* __restrict__ Ebf,
                     float* __restrict__ outF) {
    const int idx = blockIdx.x * 256 + threadIdx.x;
    const int c8 = (idx & 127) << 3;
    const ushortx8 sv = *(const ushortx8*)&S[(size_t)idx * 8];
    const float4 s0 = *(const float4*)&accum[c8];
    const float4 s1 = *(const float4*)&accum[c8 + 4];
    const float4 q0 = *(const float4*)&accum[D_MODEL + c8];
    const float4 q1 = *(const float4*)&accum[D_MODEL + c8 + 4];
    const float4 g0 = *(const float4*)&gamma[c8];
    const float4 g1 = *(const float4*)&gamma[c8 + 4];
    const float4 t0 = *(const float4*)&beta[c8];
    const float4 t1 = *(const float4*)&beta[c8 + 4];
    const float ss[8] = {s0.x, s0.y, s0.z, s0.w, s1.x, s1.y, s1.z, s1.w};
    const float qq[8] = {q0.x, q0.y, q0.z, q0.w, q1.x, q1.y, q1.z, q1.w};
    const float gg[8] = {g0.x, g0.y, g0.z, g0.w, g1.x, g1.y, g1.z, g1.w};
    const float tt[8] = {t0.x, t0.y, t0.z, t0.w, t1.x, t1.y, t1.z, t1.w};
    float o[8];
    #pragma unroll
    for (int j = 0; j < 8; ++j) {
        const float mean = ss[j] * INV_N;
        const float var = qq[j] * INV_N - mean * mean;
        const float a = gg[j] * rsqrtf(var + BN_EPS);
        o[j] = fmaf(bf2f(sv[j]), a, tt[j] - mean * a);
    }
    if (FINAL) {
        *reinterpret_cast<float4*>(&outF[(size_t)idx * 8]) =
            make_float4(o[0], o[1], o[2], o[3]);
        *reinterpret_cast<float4*>(&outF[(size_t)idx * 8 + 4]) =
            make_float4(o[4], o[5], o[6], o[7]);
    } else {
        union { unsigned int u[4]; ushortx8 s; } cv;
        cv.u[0] = cvt_pk_bf16(o[0], o[1]);
        cv.u[1] = cvt_pk_bf16(o[2], o[3]);
        cv.u[2] = cvt_pk_bf16(o[4], o[5]);
        cv.u[3] = cvt_pk_bf16(o[6], o[7]);
        *reinterpret_cast<ushortx8*>(&Ebf[(size_t)idx * 8]) = cv.s;
    }
}

// ---------------------------------------------------------------------------
extern "C" void kernel_launch(void* const* d_in, const int* in_sizes, int n_in,
                              void* d_out, int out_size, void* d_ws, size_t ws_size,
                              hipStream_t stream) {
    const float* x       = (const float*)d_in[0];
    const float* W_embed = (const float*)d_in[1];
    const float* bn1_g   = (const float*)d_in[2];
    const float* bn1_b   = (const float*)d_in[3];
    const float* Wq      = (const float*)d_in[4];
    const float* bq      = (const float*)d_in[5];
    const float* Wk      = (const float*)d_in[6];
    const float* bk      = (const float*)d_in[7];
    const float* Wv      = (const float*)d_in[8];
    const float* bv      = (const float*)d_in[9];
    const float* bng     = (const float*)d_in[10];
    const float* bnb     = (const float*)d_in[11];
    const float* Wc1     = (const float*)d_in[12];
    const float* bc1     = (const float*)d_in[13];
    const float* bn2g    = (const float*)d_in[14];
    const float* bn2b    = (const float*)d_in[15];

    const size_t NBUF = (size_t)M_ROWS * D_MODEL;
    char* ws = (char*)d_ws;
    float* accum = (float*)ws;                                   // 5*2048 f
    unsigned short* xbf   = (unsigned short*)(accum + 5 * 2048); // 262144 us
    unsigned short* Wembt = xbf + 262144;                        // 65536 us
    unsigned short* Ebf   = Wembt + 65536;                       // 4M us
    unsigned short* Sbf   = Ebf + NBUF;                          // 4M us
    unsigned short* QKVbf = Sbf + NBUF;                          // 12M us
    unsigned short* F1bf  = QKVbf;                               // alias (QKV dead)
    unsigned short* Wtqkv = QKVbf + (size_t)M_ROWS * 3072;       // 2 x 3M us
    unsigned short* Wtc1  = Wtqkv + 2 * (size_t)3145728;         // 2 x 1M us
    float* outF = (float*)d_out;

    prep_kernel<<<dim3(16, 16, 9), 256, 0, stream>>>(
        Wq, Wk, Wv, Wc1, x, W_embed, Wtqkv, Wtc1, xbf, Wembt, accum);

    // embed (bf16 MFMA, K=64, 64x128 tile -> 512 blocks) + BN1
    gemm64_bf16_kernel<2><<<dim3(8, 64), 256, 0, stream>>>(
        xbf, Wembt, nullptr, nullptr, nullptr, Sbf, nullptr, accum, 1024, 64);
    bn_apply_kernel<false><<<2048, 256, 0, stream>>>(Sbf, accum, bn1_g, bn1_b,
                                                     Ebf, nullptr);

    for (int i = 0; i < 2; ++i) {
        const size_t bo = (size_t)i * D_MODEL;
        float* accA = accum + (1 + 2 * i) * 2048;
        float* accF = accum + (2 + 2 * i) * 2048;
        const unsigned short* WtqkvL = Wtqkv + (size_t)i * 3145728;
        const unsigned short* Wtc1L  = Wtc1 + (size_t)i * 1048576;

        // QKV projection (64x128 tiles -> 1536 blocks ~4-6/CU)
        gemm64_bf16_kernel<0><<<dim3(24, 64), 256, 0, stream>>>(
            Ebf, WtqkvL, bq + bo, bk + bo, bv + bo, QKVbf, nullptr, nullptr,
            3072, 1024);
        attn_kernel<<<dim3(4, 16, 8), 256, 0, stream>>>(QKVbf, Ebf, Sbf, accA);
        bn_apply_kernel<false><<<2048, 256, 0, stream>>>(Sbf, accA, bng + bo,
                                                         bnb + bo, Ebf, nullptr);

        // FFN (64x128 tiles -> 512 blocks = 2/CU)
        gemm64_bf16_kernel<0><<<dim3(8, 64), 256, 0, stream>>>(
            Ebf, Wtc1L, bc1 + bo, bc1 + bo, bc1 + bo, F1bf, nullptr, nullptr,
            1024, 1024);
        gemm64_bf16_kernel<1><<<dim3(8, 64), 256, 0, stream>>>(
            F1bf, Wtc1L, bc1 + bo, bc1 + bo, bc1 + bo, Sbf, Ebf, accF,
            1024, 1024);
        if (i == 0)
            bn_apply_kernel<false><<<2048, 256, 0, stream>>>(Sbf, accF, bn2g + bo,
                                                             bn2b + bo, Ebf, nullptr);
        else
            bn_apply_kernel<true><<<2048, 256, 0, stream>>>(Sbf, accF, bn2g + bo,
                                                            bn2b + bo, nullptr, outF);
    }
}

// Round 14
// 260.621 us; speedup vs baseline: 1.1151x; 1.1151x over previous
//
#include <hip/hip_runtime.h>
#include <hip/hip_bf16.h>
#include <cstddef>

#define D_MODEL 1024
#define M_ROWS  4096
#define BN_EPS  1e-3f
#define C_EXP2  0.18033688011112042f   // 0.125 * log2(e)
#define INV_N   (1.0f / 4096.0f)

typedef __attribute__((ext_vector_type(8))) short short8;
typedef __attribute__((ext_vector_type(4))) short short4v;
typedef __attribute__((ext_vector_type(8))) unsigned short ushortx8;
typedef __attribute__((ext_vector_type(4))) float f32x4;

__device__ __forceinline__ unsigned short f2bf(float f) {
    __hip_bfloat16 h = __float2bfloat16(f);
    return *reinterpret_cast<unsigned short*>(&h);
}
__device__ __forceinline__ float bf2f(unsigned short u) {
    return __uint_as_float(((unsigned)u) << 16);
}
__device__ __forceinline__ unsigned int cvt_pk_bf16(float lo, float hi) {
    unsigned int r;
    asm volatile("v_cvt_pk_bf16_f32 %0, %1, %2" : "=v"(r) : "v"(lo), "v"(hi));
    return r;
}

// ---------------------------------------------------------------------------
// bf16 MFMA GEMM, 128x128 tile, BK=32, 4 waves (QKV: 768 blocks, 3/CU).
// Intensity (16 MFMA : 8 ds_read per K-step) beats extra co-residency here
// (R13 lesson: BM=64 for QKV = stage-bound, -36%).
// C = bf16(relu(A@Bt^T + bias)); bias from {b0,b1,b2} by col/1024.
// ---------------------------------------------------------------------------
template<int MODE>
__global__ __launch_bounds__(256)
void gemm_bf16_kernel(const unsigned short* __restrict__ A,
                      const unsigned short* __restrict__ Bt,
                      const float* __restrict__ b0, const float* __restrict__ b1,
                      const float* __restrict__ b2,
                      unsigned short* __restrict__ Cout,
                      const unsigned short* __restrict__ resid,
                      float* __restrict__ accp, int N, int Kd) {
    __shared__ unsigned short As[2][128 * 32];
    __shared__ unsigned short Bs[2][128 * 32];
    const int tid = threadIdx.x;
    const int lane = tid & 63;
    const int w = tid >> 6;
    const int wr = w >> 1, wc = w & 1;
    const int rowBase = blockIdx.y * 128;
    const int colBase = blockIdx.x * 128;

    const int chunk0 = w * 64 + lane;
    const int r0 = chunk0 >> 2;
    const int c0 = (chunk0 & 3) ^ ((r0 >> 1) & 3);
    const int chunk1 = 256 + chunk0;
    const int r1 = chunk1 >> 2;
    const int c1 = (chunk1 & 3) ^ ((r1 >> 1) & 3);
    const size_t aOff0 = (size_t)(rowBase + r0) * Kd + c0 * 8;
    const size_t aOff1 = (size_t)(rowBase + r1) * Kd + c1 * 8;
    const size_t bOff0 = (size_t)(colBase + r0) * Kd + c0 * 8;
    const size_t bOff1 = (size_t)(colBase + r1) * Kd + c1 * 8;
    const int ldsOff0 = (w * 64) * 8;
    const int ldsOff1 = (256 + w * 64) * 8;

    f32x4 acc[4][4];
    #pragma unroll
    for (int m = 0; m < 4; ++m)
        #pragma unroll
        for (int n = 0; n < 4; ++n)
            acc[m][n] = (f32x4){0.f, 0.f, 0.f, 0.f};

    #define STAGE(buf, kt) do {                                                   \
        const int k0_ = (kt) << 5;                                                \
        __builtin_amdgcn_global_load_lds(                                         \
            (const __attribute__((address_space(1))) void*)(A + aOff0 + k0_),     \
            (__attribute__((address_space(3))) void*)(&As[buf][ldsOff0]), 16, 0, 0);\
        __builtin_amdgcn_global_load_lds(                                         \
            (const __attribute__((address_space(1))) void*)(A + aOff1 + k0_),     \
            (__attribute__((address_space(3))) void*)(&As[buf][ldsOff1]), 16, 0, 0);\
        __builtin_amdgcn_global_load_lds(                                         \
            (const __attribute__((address_space(1))) void*)(Bt + bOff0 + k0_),    \
            (__attribute__((address_space(3))) void*)(&Bs[buf][ldsOff0]), 16, 0, 0);\
        __builtin_amdgcn_global_load_lds(                                         \
            (const __attribute__((address_space(1))) void*)(Bt + bOff1 + k0_),    \
            (__attribute__((address_space(3))) void*)(&Bs[buf][ldsOff1]), 16, 0, 0);\
    } while (0)

    const int NT = Kd >> 5;
    STAGE(0, 0);

    const int kb = lane >> 4;
    const int s = kb ^ ((lane >> 1) & 3);
    const int rA = wr * 64 + (lane & 15);
    const int rB = wc * 64 + (lane & 15);

    for (int t = 0; t < NT; ++t) {
        __syncthreads();
        if (t + 1 < NT) STAGE((t + 1) & 1, t + 1);
        const unsigned short* as = As[t & 1];
        const unsigned short* bs = Bs[t & 1];
        short8 a[4], b[4];
        #pragma unroll
        for (int m = 0; m < 4; ++m)
            a[m] = *(const short8*)&as[(rA + m * 16) * 32 + s * 8];
        #pragma unroll
        for (int n = 0; n < 4; ++n)
            b[n] = *(const short8*)&bs[(rB + n * 16) * 32 + s * 8];
        #pragma unroll
        for (int m = 0; m < 4; ++m)
            #pragma unroll
            for (int n = 0; n < 4; ++n)
                acc[m][n] = __builtin_amdgcn_mfma_f32_16x16x32_bf16(
                    a[m], b[n], acc[m][n], 0, 0, 0);
    }
    #undef STAGE

    const int cRow0 = rowBase + wr * 64 + (lane >> 4) * 4;
    const int cCol0 = colBase + wc * 64 + (lane & 15);
    #pragma unroll
    for (int n = 0; n < 4; ++n) {
        const int col = cCol0 + n * 16;
        const float* bp = (col < 1024) ? b0 : (col < 2048) ? b1 : b2;
        const float bv = bp[col & 1023];
        #pragma unroll
        for (int m = 0; m < 4; ++m)
            #pragma unroll
            for (int r = 0; r < 4; ++r) {
                const int row = cRow0 + m * 16 + r;
                const float v = fmaxf(acc[m][n][r] + bv, 0.0f);
                Cout[(size_t)row * N + col] = f2bf(v);
            }
    }
}

// ---------------------------------------------------------------------------
// bf16 MFMA GEMM, 64x128 tile, BK=32, 4 waves (2x2, wave-tile 32x64), 24KB LDS.
// For N=1024 shapes: 512 blocks = 2/CU hides the barrier drain that 1/CU
// cannot (R12 win: -15us). K-accum order identical to the 128-tile kernel.
// MODE 0: C = bf16(relu(A@Bt^T + bias))             (FFN1)
// MODE 1: S = relu(..)+resid; bf16 + channel stats  (FFN2)
// MODE 2: S = A@Bt^T; bf16 + channel stats          (embed)
// ---------------------------------------------------------------------------
template<int MODE>
__global__ __launch_bounds__(256)
void gemm64_bf16_kernel(const unsigned short* __restrict__ A,
                        const unsigned short* __restrict__ Bt,
                        const float* __restrict__ bias,
                        unsigned short* __restrict__ Cout,
                        const unsigned short* __restrict__ resid,
                        float* __restrict__ accp, int N, int Kd) {
    __shared__ unsigned short As[2][64 * 32];
    __shared__ unsigned short Bs[2][128 * 32];
    const int tid = threadIdx.x;
    const int lane = tid & 63;
    const int w = tid >> 6;
    const int wr = w >> 1, wc = w & 1;
    const int rowBase = blockIdx.y * 64;
    const int colBase = blockIdx.x * 128;

    const int ra = tid >> 2;
    const int ca = (tid & 3) ^ ((ra >> 1) & 3);
    const size_t aOff = (size_t)(rowBase + ra) * Kd + ca * 8;
    const int chunk0 = w * 64 + lane;
    const int r0 = chunk0 >> 2;
    const int c0 = (chunk0 & 3) ^ ((r0 >> 1) & 3);
    const int chunk1 = 256 + chunk0;
    const int r1 = chunk1 >> 2;
    const int c1 = (chunk1 & 3) ^ ((r1 >> 1) & 3);
    const size_t bOff0 = (size_t)(colBase + r0) * Kd + c0 * 8;
    const size_t bOff1 = (size_t)(colBase + r1) * Kd + c1 * 8;
    const int ldsA = (w * 64) * 8;
    const int ldsB0 = (w * 64) * 8;
    const int ldsB1 = (256 + w * 64) * 8;

    f32x4 acc[2][4];
    #pragma unroll
    for (int m = 0; m < 2; ++m)
        #pragma unroll
        for (int n = 0; n < 4; ++n)
            acc[m][n] = (f32x4){0.f, 0.f, 0.f, 0.f};

    #define STAGE(buf, kt) do {                                                   \
        const int k0_ = (kt) << 5;                                                \
        __builtin_amdgcn_global_load_lds(                                         \
            (const __attribute__((address_space(1))) void*)(A + aOff + k0_),      \
            (__attribute__((address_space(3))) void*)(&As[buf][ldsA]), 16, 0, 0); \
        __builtin_amdgcn_global_load_lds(                                         \
            (const __attribute__((address_space(1))) void*)(Bt + bOff0 + k0_),    \
            (__attribute__((address_space(3))) void*)(&Bs[buf][ldsB0]), 16, 0, 0);\
        __builtin_amdgcn_global_load_lds(                                         \
            (const __attribute__((address_space(1))) void*)(Bt + bOff1 + k0_),    \
            (__attribute__((address_space(3))) void*)(&Bs[buf][ldsB1]), 16, 0, 0);\
    } while (0)

    const int NT = Kd >> 5;
    STAGE(0, 0);

    const int kb = lane >> 4;
    const int s = kb ^ ((lane >> 1) & 3);
    const int rA = wr * 32 + (lane & 15);
    const int rB = wc * 64 + (lane & 15);

    for (int t = 0; t < NT; ++t) {
        __syncthreads();
        if (t + 1 < NT) STAGE((t + 1) & 1, t + 1);
        const unsigned short* as = As[t & 1];
        const unsigned short* bs = Bs[t & 1];
        short8 a[2], b[4];
        #pragma unroll
        for (int m = 0; m < 2; ++m)
            a[m] = *(const short8*)&as[(rA + m * 16) * 32 + s * 8];
        #pragma unroll
        for (int n = 0; n < 4; ++n)
            b[n] = *(const short8*)&bs[(rB + n * 16) * 32 + s * 8];
        #pragma unroll
        for (int m = 0; m < 2; ++m)
            #pragma unroll
            for (int n = 0; n < 4; ++n)
                acc[m][n] = __builtin_amdgcn_mfma_f32_16x16x32_bf16(
                    a[m], b[n], acc[m][n], 0, 0, 0);
    }
    #undef STAGE

    const int cRow0 = rowBase + wr * 32 + (lane >> 4) * 4;
    const int cCol0 = colBase + wc * 64 + (lane & 15);
    float cs[4] = {}, cq[4] = {};
    #pragma unroll
    for (int n = 0; n < 4; ++n) {
        const int col = cCol0 + n * 16;
        float bv = 0.0f;
        if (MODE != 2) bv = bias[col & 1023];
        #pragma unroll
        for (int m = 0; m < 2; ++m)
            #pragma unroll
            for (int r = 0; r < 4; ++r) {
                const int row = cRow0 + m * 16 + r;
                float v = acc[m][n][r];
                if (MODE != 2) v = fmaxf(v + bv, 0.0f);
                if (MODE == 1) v += bf2f(resid[(size_t)row * N + col]);
                if (MODE != 0) { cs[n] += v; cq[n] += v * v; }
                Cout[(size_t)row * N + col] = f2bf(v);
            }
    }
    if (MODE != 0) {
        #pragma unroll
        for (int n = 0; n < 4; ++n) {
            cs[n] += __shfl_xor(cs[n], 16); cs[n] += __shfl_xor(cs[n], 32);
            cq[n] += __shfl_xor(cq[n], 16); cq[n] += __shfl_xor(cq[n], 32);
        }
        if (lane < 16) {
            #pragma unroll
            for (int n = 0; n < 4; ++n) {
                const int col = colBase + wc * 64 + lane + n * 16;
                atomicAdd(&accp[col], cs[n]);
                atomicAdd(&accp[D_MODEL + col], cq[n]);
            }
        }
    }
}

// ---------------------------------------------------------------------------
// prep (single launch): z<8 -> weight transpose+cvt (2 layers x {Wq,Wk,Wv,Wc1});
// z==8 -> x cvt (b<128), W_embed^T (b in 128..143), zero accum (b==144)
// ---------------------------------------------------------------------------
__global__ __launch_bounds__(256)
void prep_kernel(const float* __restrict__ Wq, const float* __restrict__ Wk,
                 const float* __restrict__ Wv, const float* __restrict__ Wc1,
                 const float* __restrict__ x, const float* __restrict__ Wemb,
                 unsigned short* __restrict__ Wtqkv, unsigned short* __restrict__ Wtc1,
                 unsigned short* __restrict__ xbf, unsigned short* __restrict__ Wembt,
                 float* __restrict__ accum) {
    const int z = blockIdx.z;
    const int tid = threadIdx.x;
    if (z < 8) {
        const int layer = z >> 2, typ = z & 3;
        const size_t wo = (size_t)layer * 1048576;
        const float* src;
        unsigned short* dst;
        if (typ == 0)      { src = Wq + wo;  dst = Wtqkv + layer * 3145728; }
        else if (typ == 1) { src = Wk + wo;  dst = Wtqkv + layer * 3145728 + 1048576; }
        else if (typ == 2) { src = Wv + wo;  dst = Wtqkv + layer * 3145728 + 2097152; }
        else               { src = Wc1 + wo; dst = Wtc1 + layer * 1048576; }
        __shared__ float T[64][65];
        const int kBase = blockIdx.y * 64;
        const int nBase = blockIdx.x * 64;
        const int rr = tid >> 4;
        const int c4 = (tid & 15) * 4;
        #pragma unroll
        for (int i = 0; i < 4; ++i) {
            const int k = i * 16 + rr;
            const float4 v = *reinterpret_cast<const float4*>(
                &src[(size_t)(kBase + k) * 1024 + nBase + c4]);
            T[k][c4] = v.x; T[k][c4 + 1] = v.y; T[k][c4 + 2] = v.z; T[k][c4 + 3] = v.w;
        }
        __syncthreads();
        #pragma unroll
        for (int i = 0; i < 4; ++i) {
            const int n = i * 16 + rr;
            ushort4 o;
            o.x = f2bf(T[c4 + 0][n]); o.y = f2bf(T[c4 + 1][n]);
            o.z = f2bf(T[c4 + 2][n]); o.w = f2bf(T[c4 + 3][n]);
            *reinterpret_cast<ushort4*>(&dst[(size_t)(nBase + n) * 1024 + kBase + c4]) = o;
        }
        return;
    }
    const int b = blockIdx.y * 16 + blockIdx.x;
    if (b < 128) {
        const size_t base = (size_t)b * 2048 + tid * 8;
        const float4 v0 = *reinterpret_cast<const float4*>(&x[base]);
        const float4 v1 = *reinterpret_cast<const float4*>(&x[base + 4]);
        ushortx8 o;
        o[0] = f2bf(v0.x); o[1] = f2bf(v0.y); o[2] = f2bf(v0.z); o[3] = f2bf(v0.w);
        o[4] = f2bf(v1.x); o[5] = f2bf(v1.y); o[6] = f2bf(v1.z); o[7] = f2bf(v1.w);
        *reinterpret_cast<ushortx8*>(&xbf[base]) = o;
    } else if (b < 144) {
        __shared__ float T[64][65];
        const int nBase = (b - 128) * 64;
        const int rr = tid >> 4;
        const int c4 = (tid & 15) * 4;
        #pragma unroll
        for (int i = 0; i < 4; ++i) {
            const int k = i * 16 + rr;
            const float4 v = *reinterpret_cast<const float4*>(
                &Wemb[(size_t)k * 1024 + nBase + c4]);
            T[k][c4] = v.x; T[k][c4 + 1] = v.y; T[k][c4 + 2] = v.z; T[k][c4 + 3] = v.w;
        }
        __syncthreads();
        #pragma unroll
        for (int i = 0; i < 4; ++i) {
            const int n = i * 16 + rr;
            ushort4 o;
            o.x = f2bf(T[c4 + 0][n]); o.y = f2bf(T[c4 + 1][n]);
            o.z = f2bf(T[c4 + 2][n]); o.w = f2bf(T[c4 + 3][n]);
            *reinterpret_cast<ushort4*>(&Wembt[(size_t)(nBase + n) * 64 + c4]) = o;
        }
    } else if (b == 144) {
        for (int j = tid; j < 5 * 2048; j += 256) accum[j] = 0.0f;
    }
}

// ---------------------------------------------------------------------------
// MFMA flash attention + fused residual + BN stats. (unchanged, proven)
// ---------------------------------------------------------------------------
__global__ __launch_bounds__(256)
void attn_kernel(const unsigned short* __restrict__ QKV,
                 const unsigned short* __restrict__ Ebf,
                 unsigned short* __restrict__ Sbf,
                 float* __restrict__ accp) {
    __shared__ unsigned short Qs[128 * 64];
    __shared__ unsigned short Ks[2][64 * 64];
    __shared__ unsigned short Vt[2][64 * 72];

    const int tid = threadIdx.x;
    const int lane = tid & 63;
    const int w = tid >> 6;
    const int m = lane & 15;
    const int g = lane >> 4;
    const int l7 = lane & 7;
    const int qt = blockIdx.x, hh = blockIdx.y, bb = blockIdx.z;
    const int colB = hh * 64;
    const size_t rowQ = (size_t)bb * 512 + qt * 128;
    const size_t rowKV = (size_t)bb * 512;

    const int vk0 = (tid & 31) * 2;
    const int vcv = tid >> 5;

    #define STAGE_K(buf, kt) do {                                                  \
        const size_t kb_ = rowKV + (size_t)(kt) * 64;                              \
        _Pragma("unroll")                                                          \
        for (int i_ = 0; i_ < 2; ++i_) {                                           \
            const int c_ = w * 128 + i_ * 64 + lane;                               \
            const int r_ = c_ >> 3;                                                \
            const int gc_ = (c_ & 7) ^ (r_ & 7);                                   \
            __builtin_amdgcn_global_load_lds(                                      \
                (const __attribute__((address_space(1))) void*)                    \
                    (QKV + (kb_ + r_) * 3072 + 1024 + colB + gc_ * 8),             \
                (__attribute__((address_space(3))) void*)                          \
                    (&Ks[buf][(w * 128 + i_ * 64) * 8]), 16, 0, 0);                \
        }                                                                          \
    } while (0)

    #define LOAD_V(kt) do {                                                        \
        const size_t kb_ = rowKV + (size_t)(kt) * 64;                              \
        vst0 = *(const ushortx8*)(QKV + (kb_ + vk0) * 3072 + 2048 + colB + vcv * 8);\
        vst1 = *(const ushortx8*)(QKV + (kb_ + vk0 + 1) * 3072 + 2048 + colB + vcv * 8);\
    } while (0)

    #define WRITE_V(buf) do {                                                      \
        _Pragma("unroll")                                                          \
        for (int j_ = 0; j_ < 8; ++j_) {                                           \
            const int d_ = vcv * 8 + j_;                                           \
            unsigned int pk_ = (unsigned int)(unsigned short)vst0[j_] |            \
                               ((unsigned int)(unsigned short)vst1[j_] << 16);     \
            *(unsigned int*)&Vt[buf][d_ * 72 + vk0] = pk_;                         \
        }                                                                          \
    } while (0)

    ushortx8 vst0, vst1;

    #pragma unroll
    for (int i = 0; i < 4; ++i) {
        const int c = w * 256 + i * 64 + lane;
        const int r = c >> 3;
        const int gc = (c & 7) ^ (r & 7);
        __builtin_amdgcn_global_load_lds(
            (const __attribute__((address_space(1))) void*)
                (QKV + (rowQ + r) * 3072 + colB + gc * 8),
            (__attribute__((address_space(3))) void*)
                (&Qs[(w * 256 + i * 64) * 8]), 16, 0, 0);
    }
    STAGE_K(0, 0);
    LOAD_V(0);
    WRITE_V(0);
    __syncthreads();

    short8 qb[2][2];
    #pragma unroll
    for (int nf = 0; nf < 2; ++nf)
        #pragma unroll
        for (int ks = 0; ks < 2; ++ks)
            qb[nf][ks] = *(const short8*)&Qs[(w * 32 + 16 * nf + m) * 64 +
                                             ((g + 4 * ks) ^ l7) * 8];

    f32x4 o[2][4];
    #pragma unroll
    for (int nf = 0; nf < 2; ++nf)
        #pragma unroll
        for (int dn = 0; dn < 4; ++dn)
            o[nf][dn] = (f32x4){0.f, 0.f, 0.f, 0.f};
    float mr[2] = {-1e30f, -1e30f};
    float lsm[2] = {0.f, 0.f};

    for (int kt = 0; kt < 8; ++kt) {
        const int cur = kt & 1, nxt = cur ^ 1;
        if (kt < 7) { STAGE_K(nxt, kt + 1); LOAD_V(kt + 1); }

        f32x4 st[4][2];
        #pragma unroll
        for (int mf = 0; mf < 4; ++mf)
            #pragma unroll
            for (int nf = 0; nf < 2; ++nf)
                st[mf][nf] = (f32x4){0.f, 0.f, 0.f, 0.f};
        #pragma unroll
        for (int ks = 0; ks < 2; ++ks) {
            short8 a[4];
            #pragma unroll
            for (int mf = 0; mf < 4; ++mf)
                a[mf] = *(const short8*)&Ks[cur][(m + 16 * mf) * 64 +
                                                 ((g + 4 * ks) ^ l7) * 8];
            __builtin_amdgcn_s_setprio(1);
            #pragma unroll
            for (int mf = 0; mf < 4; ++mf)
                #pragma unroll
                for (int nf = 0; nf < 2; ++nf)
                    st[mf][nf] = __builtin_amdgcn_mfma_f32_16x16x32_bf16(
                        a[mf], qb[nf][ks], st[mf][nf], 0, 0, 0);
            __builtin_amdgcn_s_setprio(0);
        }

        float pmax[2];
        #pragma unroll
        for (int nf = 0; nf < 2; ++nf) {
            float a0 = fmaxf(fmaxf(st[0][nf][0], st[0][nf][1]),
                             fmaxf(st[0][nf][2], st[0][nf][3]));
            float a1 = fmaxf(fmaxf(st[1][nf][0], st[1][nf][1]),
                             fmaxf(st[1][nf][2], st[1][nf][3]));
            float a2 = fmaxf(fmaxf(st[2][nf][0], st[2][nf][1]),
                             fmaxf(st[2][nf][2], st[2][nf][3]));
            float a3 = fmaxf(fmaxf(st[3][nf][0], st[3][nf][1]),
                             fmaxf(st[3][nf][2], st[3][nf][3]));
            float mx = fmaxf(fmaxf(a0, a1), fmaxf(a2, a3));
            mx = fmaxf(mx, __shfl_xor(mx, 16));
            mx = fmaxf(mx, __shfl_xor(mx, 32));
            pmax[nf] = mx;
        }
        const int need = (pmax[0] - mr[0] > 64.f) || (pmax[1] - mr[1] > 64.f);
        if (__any(need)) {
            float al[2];
            #pragma unroll
            for (int nf = 0; nf < 2; ++nf) {
                const float mn = fmaxf(mr[nf], pmax[nf]);
                al[nf] = exp2f((mr[nf] - mn) * C_EXP2);
                lsm[nf] *= al[nf];
                mr[nf] = mn;
            }
            #pragma unroll
            for (int nf = 0; nf < 2; ++nf)
                #pragma unroll
                for (int r = 0; r < 4; ++r) {
                    const float av = __shfl(al[nf], 4 * g + r);
                    #pragma unroll
                    for (int dn = 0; dn < 4; ++dn)
                        o[nf][dn][r] *= av;
                }
        }

        float pf[2][4][4];
        #pragma unroll
        for (int nf = 0; nf < 2; ++nf) {
            const float mc = mr[nf] * C_EXP2;
            float s0 = 0.f, s1 = 0.f, s2 = 0.f, s3 = 0.f;
            #pragma unroll
            for (int mf = 0; mf < 4; ++mf) {
                float p0 = exp2f(fmaf(st[mf][nf][0], C_EXP2, -mc));
                float p1 = exp2f(fmaf(st[mf][nf][1], C_EXP2, -mc));
                float p2 = exp2f(fmaf(st[mf][nf][2], C_EXP2, -mc));
                float p3 = exp2f(fmaf(st[mf][nf][3], C_EXP2, -mc));
                pf[nf][mf][0] = p0; pf[nf][mf][1] = p1;
                pf[nf][mf][2] = p2; pf[nf][mf][3] = p3;
                s0 += p0; s1 += p1; s2 += p2; s3 += p3;
            }
            float ls = (s0 + s1) + (s2 + s3);
            ls += __shfl_xor(ls, 16);
            ls += __shfl_xor(ls, 32);
            lsm[nf] += ls;
        }

        if (kt < 7) WRITE_V(nxt);

        short8 pb[2][2];
        #pragma unroll
        for (int nf = 0; nf < 2; ++nf)
            #pragma unroll
            for (int ks = 0; ks < 2; ++ks) {
                union { unsigned int u[4]; short8 s; } cv;
                cv.u[0] = cvt_pk_bf16(pf[nf][2 * ks][0], pf[nf][2 * ks][1]);
                cv.u[1] = cvt_pk_bf16(pf[nf][2 * ks][2], pf[nf][2 * ks][3]);
                cv.u[2] = cvt_pk_bf16(pf[nf][2 * ks + 1][0], pf[nf][2 * ks + 1][1]);
                cv.u[3] = cvt_pk_bf16(pf[nf][2 * ks + 1][2], pf[nf][2 * ks + 1][3]);
                pb[nf][ks] = cv.s;
            }

        #pragma unroll
        for (int ks = 0; ks < 2; ++ks) {
            short8 vb[4];
            #pragma unroll
            for (int dn = 0; dn < 4; ++dn) {
                const int d = m + 16 * dn;
                const short4v lo = *(const short4v*)&Vt[cur][d * 72 + 4 * g + 32 * ks];
                const short4v hi = *(const short4v*)&Vt[cur][d * 72 + 4 * g + 16 + 32 * ks];
                vb[dn] = __builtin_shufflevector(lo, hi, 0, 1, 2, 3, 4, 5, 6, 7);
            }
            __builtin_amdgcn_s_setprio(1);
            #pragma unroll
            for (int nf = 0; nf < 2; ++nf)
                #pragma unroll
                for (int dn = 0; dn < 4; ++dn)
                    o[nf][dn] = __builtin_amdgcn_mfma_f32_16x16x32_bf16(
                        pb[nf][ks], vb[dn], o[nf][dn], 0, 0, 0);
            __builtin_amdgcn_s_setprio(0);
        }
        __syncthreads();
    }

    float cs[4] = {}, cq[4] = {};
    #pragma unroll
    for (int nf = 0; nf < 2; ++nf) {
        const float inv = 1.0f / lsm[nf];
        #pragma unroll
        for (int r = 0; r < 4; ++r) {
            const float sc = __shfl(inv, 4 * g + r);
            const size_t row = rowQ + w * 32 + 16 * nf + 4 * g + r;
            #pragma unroll
            for (int dn = 0; dn < 4; ++dn) {
                const int ch = colB + 16 * dn + m;
                const float sv = o[nf][dn][r] * sc + bf2f(Ebf[row * D_MODEL + ch]);
                Sbf[row * D_MODEL + ch] = f2bf(sv);
                cs[dn] += sv; cq[dn] += sv * sv;
            }
        }
    }
    #pragma unroll
    for (int dn = 0; dn < 4; ++dn) {
        cs[dn] += __shfl_xor(cs[dn], 16); cs[dn] += __shfl_xor(cs[dn], 32);
        cq[dn] += __shfl_xor(cq[dn], 16); cq[dn] += __shfl_xor(cq[dn], 32);
    }
    if (lane < 16) {
        #pragma unroll
        for (int dn = 0; dn < 4; ++dn) {
            atomicAdd(&accp[colB + 16 * dn + lane], cs[dn]);
            atomicAdd(&accp[D_MODEL + colB + 16 * dn + lane], cq[dn]);
        }
    }
    #undef STAGE_K
    #undef LOAD_V
    #undef WRITE_V
}

// ---------------------------------------------------------------------------
// BN apply with inlined stats->coef (unchanged, proven)
// ---------------------------------------------------------------------------
template<bool FINAL>
__global__ __launch_bounds__(256)
void bn_apply_kernel(const unsigned short* __restrict__ S,
                     const float* __restrict__ accum,
                     const float* __restrict__ gamma,
                     const float* __restrict__ beta,
                     unsigned short* __restrict__ Ebf,
                     float* __restrict__ outF) {
    const int idx = blockIdx.x * 256 + threadIdx.x;
    const int c8 = (idx & 127) << 3;
    const ushortx8 sv = *(const ushortx8*)&S[(size_t)idx * 8];
    const float4 s0 = *(const float4*)&accum[c8];
    const float4 s1 = *(const float4*)&accum[c8 + 4];
    const float4 q0 = *(const float4*)&accum[D_MODEL + c8];
    const float4 q1 = *(const float4*)&accum[D_MODEL + c8 + 4];
    const float4 g0 = *(const float4*)&gamma[c8];
    const float4 g1 = *(const float4*)&gamma[c8 + 4];
    const float4 t0 = *(const float4*)&beta[c8];
    const float4 t1 = *(const float4*)&beta[c8 + 4];
    const float ss[8] = {s0.x, s0.y, s0.z, s0.w, s1.x, s1.y, s1.z, s1.w};
    const float qq[8] = {q0.x, q0.y, q0.z, q0.w, q1.x, q1.y, q1.z, q1.w};
    const float gg[8] = {g0.x, g0.y, g0.z, g0.w, g1.x, g1.y, g1.z, g1.w};
    const float tt[8] = {t0.x, t0.y, t0.z, t0.w, t1.x, t1.y, t1.z, t1.w};
    float o[8];
    #pragma unroll
    for (int j = 0; j < 8; ++j) {
        const float mean = ss[j] * INV_N;
        const float var = qq[j] * INV_N - mean * mean;
        const float a = gg[j] * rsqrtf(var + BN_EPS);
        o[j] = fmaf(bf2f(sv[j]), a, tt[j] - mean * a);
    }
    if (FINAL) {
        *reinterpret_cast<float4*>(&outF[(size_t)idx * 8]) =
            make_float4(o[0], o[1], o[2], o[3]);
        *reinterpret_cast<float4*>(&outF[(size_t)idx * 8 + 4]) =
            make_float4(o[4], o[5], o[6], o[7]);
    } else {
        union { unsigned int u[4]; ushortx8 s; } cv;
        cv.u[0] = cvt_pk_bf16(o[0], o[1]);
        cv.u[1] = cvt_pk_bf16(o[2], o[3]);
        cv.u[2] = cvt_pk_bf16(o[4], o[5]);
        cv.u[3] = cvt_pk_bf16(o[6], o[7]);
        *reinterpret_cast<ushortx8*>(&Ebf[(size_t)idx * 8]) = cv.s;
    }
}

// ---------------------------------------------------------------------------
extern "C" void kernel_launch(void* const* d_in, const int* in_sizes, int n_in,
                              void* d_out, int out_size, void* d_ws, size_t ws_size,
                              hipStream_t stream) {
    const float* x       = (const float*)d_in[0];
    const float* W_embed = (const float*)d_in[1];
    const float* bn1_g   = (const float*)d_in[2];
    const float* bn1_b   = (const float*)d_in[3];
    const float* Wq      = (const float*)d_in[4];
    const float* bq      = (const float*)d_in[5];
    const float* Wk      = (const float*)d_in[6];
    const float* bk      = (const float*)d_in[7];
    const float* Wv      = (const float*)d_in[8];
    const float* bv      = (const float*)d_in[9];
    const float* bng     = (const float*)d_in[10];
    const float* bnb     = (const float*)d_in[11];
    const float* Wc1     = (const float*)d_in[12];
    const float* bc1     = (const float*)d_in[13];
    const float* bn2g    = (const float*)d_in[14];
    const float* bn2b    = (const float*)d_in[15];

    const size_t NBUF = (size_t)M_ROWS * D_MODEL;
    char* ws = (char*)d_ws;
    float* accum = (float*)ws;                                   // 5*2048 f
    unsigned short* xbf   = (unsigned short*)(accum + 5 * 2048); // 262144 us
    unsigned short* Wembt = xbf + 262144;                        // 65536 us
    unsigned short* Ebf   = Wembt + 65536;                       // 4M us
    unsigned short* Sbf   = Ebf + NBUF;                          // 4M us
    unsigned short* QKVbf = Sbf + NBUF;                          // 12M us
    unsigned short* F1bf  = QKVbf;                               // alias (QKV dead)
    unsigned short* Wtqkv = QKVbf + (size_t)M_ROWS * 3072;       // 2 x 3M us
    unsigned short* Wtc1  = Wtqkv + 2 * (size_t)3145728;         // 2 x 1M us
    float* outF = (float*)d_out;

    prep_kernel<<<dim3(16, 16, 9), 256, 0, stream>>>(
        Wq, Wk, Wv, Wc1, x, W_embed, Wtqkv, Wtc1, xbf, Wembt, accum);

    // embed (bf16 MFMA, K=64, 64x128 tile -> 512 blocks) + BN1
    gemm64_bf16_kernel<2><<<dim3(8, 64), 256, 0, stream>>>(
        xbf, Wembt, nullptr, Sbf, nullptr, accum, 1024, 64);
    bn_apply_kernel<false><<<2048, 256, 0, stream>>>(Sbf, accum, bn1_g, bn1_b,
                                                     Ebf, nullptr);

    for (int i = 0; i < 2; ++i) {
        const size_t bo = (size_t)i * D_MODEL;
        float* accA = accum + (1 + 2 * i) * 2048;
        float* accF = accum + (2 + 2 * i) * 2048;
        const unsigned short* WtqkvL = Wtqkv + (size_t)i * 3145728;
        const unsigned short* Wtc1L  = Wtc1 + (size_t)i * 1048576;

        // QKV projection (128x128 tiles -> 768 blocks = 3/CU; intensity wins)
        gemm_bf16_kernel<0><<<dim3(24, 32), 256, 0, stream>>>(
            Ebf, WtqkvL, bq + bo, bk + bo, bv + bo, QKVbf, nullptr, nullptr,
            3072, 1024);
        attn_kernel<<<dim3(4, 16, 8), 256, 0, stream>>>(QKVbf, Ebf, Sbf, accA);
        bn_apply_kernel<false><<<2048, 256, 0, stream>>>(Sbf, accA, bng + bo,
                                                         bnb + bo, Ebf, nullptr);

        // FFN (64x128 tiles -> 512 blocks = 2/CU)
        gemm64_bf16_kernel<0><<<dim3(8, 64), 256, 0, stream>>>(
            Ebf, Wtc1L, bc1 + bo, F1bf, nullptr, nullptr, 1024, 1024);
        gemm64_bf16_kernel<1><<<dim3(8, 64), 256, 0, stream>>>(
            F1bf, Wtc1L, bc1 + bo, Sbf, Ebf, accF, 1024, 1024);
        if (i == 0)
            bn_apply_kernel<false><<<2048, 256, 0, stream>>>(Sbf, accF, bn2g + bo,
                                                             bn2b + bo, Ebf, nullptr);
        else
            bn_apply_kernel<true><<<2048, 256, 0, stream>>>(Sbf, accF, bn2g + bo,
                                                            bn2b + bo, nullptr, outF);
    }
}